// Round 1
// baseline (231.307 us; speedup 1.0000x reference)
//
#include <hip/hip_runtime.h>
#include <math.h>

#define Bb 2
#define Nn 100000
#define Kk 16
#define Ff 128
#define Cc 10

// ---------------------------------------------------------------------------
// Kernel 1: mp[b,n,:] = mean_k x[b, idx[b,n,k], :]
// One 64-lane wave per node; lane owns a float2 (columns 2*lane, 2*lane+1).
// ---------------------------------------------------------------------------
__global__ __launch_bounds__(256) void sage_mp_kernel(
    const float* __restrict__ x,      // (B, N, F)
    const int*   __restrict__ idx,    // (B, N, K)
    float*       __restrict__ mp_out) // (B, N, F), at d_out + 20
{
    const int wavesPerBlock = 256 / 64;
    int node = blockIdx.x * wavesPerBlock + (threadIdx.x >> 6);
    const int total = Bb * Nn;
    if (node >= total) return;

    int lane = threadIdx.x & 63;
    int b = node / Nn;                  // 0 or 1
    const float* xb = x + (size_t)b * Nn * Ff;
    const int*   ip = idx + (size_t)node * Kk;

    float2 acc = make_float2(0.f, 0.f);
#pragma unroll
    for (int k = 0; k < Kk; ++k) {
        int j = ip[k];                  // wave-uniform broadcast load
        const float2* row = (const float2*)(xb + (size_t)j * Ff);
        float2 v = row[lane];           // 64 lanes x 8B = 512B coalesced
        acc.x += v.x;
        acc.y += v.y;
    }
    acc.x *= (1.0f / Kk);
    acc.y *= (1.0f / Kk);

    ((float2*)(mp_out + (size_t)node * Ff))[lane] = acc;
}

// ---------------------------------------------------------------------------
// Kernel 2: the tiny MLP head. Single block of 128 threads.
// old_vec = mean_k x[b, idx[b,0,k], :]; new_vec = x[b,0,:]
// a = relu(old @ W1 + b1); bb = relu(new @ W2 + b2)
// probs = softmax([a,bb] @ Wo + bo)
// ---------------------------------------------------------------------------
__global__ __launch_bounds__(128) void sage_head_kernel(
    const float* __restrict__ x,     // (B, N, F)
    const int*   __restrict__ idx,   // (B, N, K)
    const float* __restrict__ W1,    // (F, 64)
    const float* __restrict__ b1,    // (64,)
    const float* __restrict__ W2,    // (F, 64)
    const float* __restrict__ b2,    // (64,)
    const float* __restrict__ Wo,    // (128, C)
    const float* __restrict__ bo,    // (C,)
    float*       __restrict__ out)   // probs at d_out[0..19]
{
    __shared__ float old_s[Bb][Ff];
    __shared__ float new_s[Bb][Ff];
    __shared__ float h[Bb][Ff];
    __shared__ float logits[Bb][Cc];

    int t = threadIdx.x;  // 0..127

    // Stage old_vec / new_vec
    for (int b = 0; b < Bb; ++b) {
        const float* xb = x + (size_t)b * Nn * Ff;
        const int*   ip = idx + (size_t)b * Nn * Kk;  // node 0 of batch b
        float s = 0.f;
#pragma unroll
        for (int k = 0; k < Kk; ++k)
            s += xb[(size_t)ip[k] * Ff + t];
        old_s[b][t] = s * (1.0f / Kk);
        new_s[b][t] = xb[t];
    }
    __syncthreads();

    // Hidden layer: thread t computes concat-column t for both batches.
    for (int b = 0; b < Bb; ++b) {
        float s;
        if (t < 64) {
            s = b1[t];
            for (int f = 0; f < Ff; ++f)
                s = fmaf(old_s[b][f], W1[f * 64 + t], s);
        } else {
            int j = t - 64;
            s = b2[j];
            for (int f = 0; f < Ff; ++f)
                s = fmaf(new_s[b][f], W2[f * 64 + j], s);
        }
        h[b][t] = fmaxf(s, 0.f);
    }
    __syncthreads();

    // Output layer: 20 (b,c) pairs
    if (t < Bb * Cc) {
        int b = t / Cc, c = t % Cc;
        float s = bo[c];
        for (int j = 0; j < 128; ++j)
            s = fmaf(h[b][j], Wo[j * Cc + c], s);
        logits[b][c] = s;
    }
    __syncthreads();

    // Softmax per batch (serial, tiny)
    if (t < Bb) {
        float m = -1e30f;
        for (int c = 0; c < Cc; ++c) m = fmaxf(m, logits[t][c]);
        float e[Cc];
        float sum = 0.f;
        for (int c = 0; c < Cc; ++c) { e[c] = expf(logits[t][c] - m); sum += e[c]; }
        float inv = 1.0f / sum;
        for (int c = 0; c < Cc; ++c) out[t * Cc + c] = e[c] * inv;
    }
}

extern "C" void kernel_launch(void* const* d_in, const int* in_sizes, int n_in,
                              void* d_out, int out_size, void* d_ws, size_t ws_size,
                              hipStream_t stream) {
    const float* x   = (const float*)d_in[0];
    const int*   idx = (const int*)d_in[1];
    const float* W1  = (const float*)d_in[2];
    const float* b1  = (const float*)d_in[3];
    const float* W2  = (const float*)d_in[4];
    const float* b2  = (const float*)d_in[5];
    const float* Wo  = (const float*)d_in[6];
    const float* bo  = (const float*)d_in[7];

    float* out   = (float*)d_out;         // probs: first 20 floats
    float* mp_out = out + Bb * Cc;        // mp: next B*N*F floats (offset 80B, 16B-aligned)

    const int total = Bb * Nn;            // 200000 nodes
    const int wavesPerBlock = 4;          // 256 threads
    int grid = (total + wavesPerBlock - 1) / wavesPerBlock;

    sage_mp_kernel<<<grid, 256, 0, stream>>>(x, idx, mp_out);
    sage_head_kernel<<<1, 128, 0, stream>>>(x, idx, W1, b1, W2, b2, Wo, bo, out);
}

// Round 2
// 159.038 us; speedup vs baseline: 1.4544x; 1.4544x over previous
//
#include <hip/hip_runtime.h>
#include <math.h>

#define Bb 2
#define Nn 100000
#define Kk 16
#define Ff 128
#define Cc 10

// ---------------------------------------------------------------------------
// f32 -> bf16 (RNE) helper
// ---------------------------------------------------------------------------
__device__ __forceinline__ unsigned short f2bf(float f) {
    unsigned int u = __float_as_uint(f);
    u = (u + 0x7fffu + ((u >> 16) & 1u)) >> 16;
    return (unsigned short)u;
}

// ---------------------------------------------------------------------------
// Kernel 0: stream-convert x (f32) -> xh (bf16) in d_ws.
// Each thread handles 8 elements: 32B read, 16B write.
// ---------------------------------------------------------------------------
__global__ __launch_bounds__(256) void convert_bf16_kernel(
    const float* __restrict__ x, unsigned int* __restrict__ xh4 /* uint4-granular */)
{
    const int total8 = Bb * Nn * Ff / 8;   // 3,200,000
    int i = blockIdx.x * 256 + threadIdx.x;
    int stride = gridDim.x * 256;
    for (; i < total8; i += stride) {
        const float4* p = (const float4*)(x + (size_t)i * 8);
        float4 a = p[0];
        float4 b = p[1];
        uint4 o;
        o.x = (unsigned int)f2bf(a.x) | ((unsigned int)f2bf(a.y) << 16);
        o.y = (unsigned int)f2bf(a.z) | ((unsigned int)f2bf(a.w) << 16);
        o.z = (unsigned int)f2bf(b.x) | ((unsigned int)f2bf(b.y) << 16);
        o.w = (unsigned int)f2bf(b.z) | ((unsigned int)f2bf(b.w) << 16);
        ((uint4*)xh4)[i] = o;
    }
}

// ---------------------------------------------------------------------------
// Kernel 1 (bf16 path): mp[b,n,:] = mean_k xh[b, idx[b,n,k], :]
// One wave per node (4 nodes sequentially per wave).
// Lane layout: g = lane>>4 (row-group), c = lane&15 (column-group of 8).
// Iteration t: group g loads row idx[t*4+g] columns c*8..c*8+7 as uint4
// (16B/lane, 4 rows per wave instruction). f32 accumulate, shfl_xor reduce.
// ---------------------------------------------------------------------------
#define NODES_PER_WAVE 4
__global__ __launch_bounds__(256) void sage_mp_bf16_kernel(
    const unsigned short* __restrict__ xh,  // (B, N, F) bf16
    const int*            __restrict__ idx, // (B, N, K)
    float*                __restrict__ mp_out)
{
    int wave = (blockIdx.x * 256 + threadIdx.x) >> 6;
    int lane = threadIdx.x & 63;
    int g = lane >> 4;
    int c = lane & 15;
    int node0 = wave * NODES_PER_WAVE;

#pragma unroll 1
    for (int u = 0; u < NODES_PER_WAVE; ++u) {
        int nd = node0 + u;
        if (nd >= Bb * Nn) return;
        const unsigned short* xb = xh + (nd >= Nn ? (size_t)Nn * Ff : 0);
        const int* ip = idx + (size_t)nd * Kk;
        int pre = ip[c];   // lanes 0..15 carry idx[0..15] (others duplicate)

        float acc[8];
#pragma unroll
        for (int j = 0; j < 8; ++j) acc[j] = 0.f;

#pragma unroll
        for (int t = 0; t < 4; ++t) {
            int r = __shfl(pre, t * 4 + g, 64);
            uint4 v = *(const uint4*)(xb + (size_t)r * Ff + c * 8);
            unsigned int w0 = v.x, w1 = v.y, w2 = v.z, w3 = v.w;
            acc[0] += __uint_as_float(w0 << 16);
            acc[1] += __uint_as_float(w0 & 0xffff0000u);
            acc[2] += __uint_as_float(w1 << 16);
            acc[3] += __uint_as_float(w1 & 0xffff0000u);
            acc[4] += __uint_as_float(w2 << 16);
            acc[5] += __uint_as_float(w2 & 0xffff0000u);
            acc[6] += __uint_as_float(w3 << 16);
            acc[7] += __uint_as_float(w3 & 0xffff0000u);
        }

#pragma unroll
        for (int j = 0; j < 8; ++j) {
            acc[j] += __shfl_xor(acc[j], 16, 64);
            acc[j] += __shfl_xor(acc[j], 32, 64);
        }

        float2 wv = make_float2(acc[2 * g] * (1.f / 16.f),
                                acc[2 * g + 1] * (1.f / 16.f));
        float* op = mp_out + (size_t)nd * Ff + c * 8 + 2 * g;
        union { float2 f; unsigned long long u; } cv;
        cv.f = wv;
        __builtin_nontemporal_store(cv.u, (unsigned long long*)op);
    }
}

// ---------------------------------------------------------------------------
// Kernel 1 (fallback f32 path, used only if ws too small)
// ---------------------------------------------------------------------------
__global__ __launch_bounds__(256) void sage_mp_kernel(
    const float* __restrict__ x,
    const int*   __restrict__ idx,
    float*       __restrict__ mp_out)
{
    const int wavesPerBlock = 256 / 64;
    int node = blockIdx.x * wavesPerBlock + (threadIdx.x >> 6);
    if (node >= Bb * Nn) return;
    int lane = threadIdx.x & 63;
    const float* xb = x + (node >= Nn ? (size_t)Nn * Ff : 0);
    const int* ip = idx + (size_t)node * Kk;
    float2 acc = make_float2(0.f, 0.f);
#pragma unroll
    for (int k = 0; k < Kk; ++k) {
        int j = ip[k];
        float2 v = ((const float2*)(xb + (size_t)j * Ff))[lane];
        acc.x += v.x; acc.y += v.y;
    }
    acc.x *= (1.0f / Kk); acc.y *= (1.0f / Kk);
    ((float2*)(mp_out + (size_t)node * Ff))[lane] = acc;
}

// ---------------------------------------------------------------------------
// Kernel 2: tiny MLP head (f32, reads original x). Single block, 128 threads.
// ---------------------------------------------------------------------------
__global__ __launch_bounds__(128) void sage_head_kernel(
    const float* __restrict__ x,
    const int*   __restrict__ idx,
    const float* __restrict__ W1, const float* __restrict__ b1,
    const float* __restrict__ W2, const float* __restrict__ b2,
    const float* __restrict__ Wo, const float* __restrict__ bo,
    float*       __restrict__ out)
{
    __shared__ float old_s[Bb][Ff];
    __shared__ float new_s[Bb][Ff];
    __shared__ float h[Bb][Ff];
    __shared__ float logits[Bb][Cc];

    int t = threadIdx.x;

    for (int b = 0; b < Bb; ++b) {
        const float* xb = x + (size_t)b * Nn * Ff;
        const int*   ip = idx + (size_t)b * Nn * Kk;
        float s = 0.f;
#pragma unroll
        for (int k = 0; k < Kk; ++k)
            s += xb[(size_t)ip[k] * Ff + t];
        old_s[b][t] = s * (1.0f / Kk);
        new_s[b][t] = xb[t];
    }
    __syncthreads();

    for (int b = 0; b < Bb; ++b) {
        float s;
        if (t < 64) {
            s = b1[t];
            for (int f = 0; f < Ff; ++f)
                s = fmaf(old_s[b][f], W1[f * 64 + t], s);
        } else {
            int j = t - 64;
            s = b2[j];
            for (int f = 0; f < Ff; ++f)
                s = fmaf(new_s[b][f], W2[f * 64 + j], s);
        }
        h[b][t] = fmaxf(s, 0.f);
    }
    __syncthreads();

    if (t < Bb * Cc) {
        int b = t / Cc, c = t % Cc;
        float s = bo[c];
        for (int j = 0; j < 128; ++j)
            s = fmaf(h[b][j], Wo[j * Cc + c], s);
        logits[b][c] = s;
    }
    __syncthreads();

    if (t < Bb) {
        float m = -1e30f;
        for (int c = 0; c < Cc; ++c) m = fmaxf(m, logits[t][c]);
        float e[Cc];
        float sum = 0.f;
        for (int c = 0; c < Cc; ++c) { e[c] = expf(logits[t][c] - m); sum += e[c]; }
        float inv = 1.0f / sum;
        for (int c = 0; c < Cc; ++c) out[t * Cc + c] = e[c] * inv;
    }
}

extern "C" void kernel_launch(void* const* d_in, const int* in_sizes, int n_in,
                              void* d_out, int out_size, void* d_ws, size_t ws_size,
                              hipStream_t stream) {
    const float* x   = (const float*)d_in[0];
    const int*   idx = (const int*)d_in[1];
    const float* W1  = (const float*)d_in[2];
    const float* b1  = (const float*)d_in[3];
    const float* W2  = (const float*)d_in[4];
    const float* b2  = (const float*)d_in[5];
    const float* Wo  = (const float*)d_in[6];
    const float* bo  = (const float*)d_in[7];

    float* out    = (float*)d_out;
    float* mp_out = out + Bb * Cc;   // mp at 80B offset (16B aligned)

    const size_t bf16_bytes = (size_t)Bb * Nn * Ff * 2;  // 51.2 MB

    if (ws_size >= bf16_bytes) {
        unsigned int* xh = (unsigned int*)d_ws;
        convert_bf16_kernel<<<2048, 256, 0, stream>>>(x, xh);
        const int totalWaves = (Bb * Nn + NODES_PER_WAVE - 1) / NODES_PER_WAVE; // 50000
        const int grid = (totalWaves + 3) / 4;                                   // 12500
        sage_mp_bf16_kernel<<<grid, 256, 0, stream>>>(
            (const unsigned short*)xh, idx, mp_out);
    } else {
        const int total = Bb * Nn;
        int grid = (total + 3) / 4;
        sage_mp_kernel<<<grid, 256, 0, stream>>>(x, idx, mp_out);
    }
    sage_head_kernel<<<1, 128, 0, stream>>>(x, idx, W1, b1, W2, b2, Wo, bo, out);
}

// Round 4
// 103.523 us; speedup vs baseline: 2.2344x; 1.5363x over previous
//
#include <hip/hip_runtime.h>
#include <math.h>

#define Bb 2
#define Nn 100000
#define Kk 16
#define Ff 128
#define Cc 10
#define QROWS (Bb * Nn)          // 200000
#define QBLOCKS 12500            // quant kernel: 16 rows/block

// ---------------------------------------------------------------------------
// MLP head helper (128+ threads; guards per-phase).
// ---------------------------------------------------------------------------
__device__ __forceinline__ void head_compute(
    const float* __restrict__ x, const int* __restrict__ idx,
    const float* __restrict__ W1, const float* __restrict__ b1,
    const float* __restrict__ W2, const float* __restrict__ b2,
    const float* __restrict__ Wo, const float* __restrict__ bo,
    float* __restrict__ out)
{
    __shared__ float old_s[Bb][Ff];
    __shared__ float new_s[Bb][Ff];
    __shared__ float h[Bb][Ff];
    __shared__ float logits[Bb][Cc];
    int t = threadIdx.x;

    if (t < Ff) {
        for (int b = 0; b < Bb; ++b) {
            const float* xb = x + (size_t)b * Nn * Ff;
            const int*   ip = idx + (size_t)b * Nn * Kk;
            float s = 0.f;
#pragma unroll
            for (int k = 0; k < Kk; ++k)
                s += xb[(size_t)ip[k] * Ff + t];
            old_s[b][t] = s * (1.0f / Kk);
            new_s[b][t] = xb[t];
        }
    }
    __syncthreads();

    if (t < Ff) {
        for (int b = 0; b < Bb; ++b) {
            float s;
            if (t < 64) {
                s = b1[t];
                for (int f = 0; f < Ff; ++f)
                    s = fmaf(old_s[b][f], W1[f * 64 + t], s);
            } else {
                int j = t - 64;
                s = b2[j];
                for (int f = 0; f < Ff; ++f)
                    s = fmaf(new_s[b][f], W2[f * 64 + j], s);
            }
            h[b][t] = fmaxf(s, 0.f);
        }
    }
    __syncthreads();

    if (t < Bb * Cc) {
        int b = t / Cc, c = t % Cc;
        float s = bo[c];
        for (int j = 0; j < 128; ++j)
            s = fmaf(h[b][j], Wo[j * Cc + c], s);
        logits[b][c] = s;
    }
    __syncthreads();

    if (t < Bb) {
        float m = -1e30f;
        for (int c = 0; c < Cc; ++c) m = fmaxf(m, logits[t][c]);
        float e[Cc];
        float sum = 0.f;
        for (int c = 0; c < Cc; ++c) { e[c] = expf(logits[t][c] - m); sum += e[c]; }
        float inv = 1.0f / sum;
        for (int c = 0; c < Cc; ++c) out[t * Cc + c] = e[c] * inv;
    }
}

// ---------------------------------------------------------------------------
// Kernel 0: quantize x -> per-row-scaled u8 (biased +128). PURE producer.
// Row = 128 bytes; 16-lane group per row (8 f32 / lane).
// scale[row] = rowmax/127; q = rint(x*127/rowmax) + 128.
// ---------------------------------------------------------------------------
__global__ __launch_bounds__(256) void quant_kernel(
    const float* __restrict__ x,
    unsigned char* __restrict__ xq, float* __restrict__ scales)
{
    int wave = threadIdx.x >> 6;
    int lane = threadIdx.x & 63;
    int g = lane >> 4, c = lane & 15;
    int row = blockIdx.x * 16 + wave * 4 + g;    // 12500*16 = 200000 exactly

    const float* xr = x + (size_t)row * Ff + c * 8;
    float4 a  = *(const float4*)xr;
    float4 bv = *(const float4*)(xr + 4);

    float m = fmaxf(fmaxf(fmaxf(fabsf(a.x), fabsf(a.y)), fmaxf(fabsf(a.z), fabsf(a.w))),
                    fmaxf(fmaxf(fabsf(bv.x), fabsf(bv.y)), fmaxf(fabsf(bv.z), fabsf(bv.w))));
    m = fmaxf(m, __shfl_xor(m, 1, 64));
    m = fmaxf(m, __shfl_xor(m, 2, 64));
    m = fmaxf(m, __shfl_xor(m, 4, 64));
    m = fmaxf(m, __shfl_xor(m, 8, 64));
    m = fmaxf(m, 1e-20f);
    float inv = 127.0f / m;

    unsigned q0 = (unsigned)((int)rintf(a.x * inv) + 128);
    unsigned q1 = (unsigned)((int)rintf(a.y * inv) + 128);
    unsigned q2 = (unsigned)((int)rintf(a.z * inv) + 128);
    unsigned q3 = (unsigned)((int)rintf(a.w * inv) + 128);
    unsigned q4 = (unsigned)((int)rintf(bv.x * inv) + 128);
    unsigned q5 = (unsigned)((int)rintf(bv.y * inv) + 128);
    unsigned q6 = (unsigned)((int)rintf(bv.z * inv) + 128);
    unsigned q7 = (unsigned)((int)rintf(bv.w * inv) + 128);

    uint2 o;
    o.x = q0 | (q1 << 8) | (q2 << 16) | (q3 << 24);
    o.y = q4 | (q5 << 8) | (q6 << 16) | (q7 << 24);
    *(uint2*)(xq + (size_t)row * Ff + c * 8) = o;
    if (c == 0) scales[row] = m * (1.0f / 127.0f);
}

// ---------------------------------------------------------------------------
// Kernel 1: standalone MLP head (between producer and consumer; also adds
// one extra kernel-boundary release/acquire between quant and mp).
// ---------------------------------------------------------------------------
__global__ __launch_bounds__(128) void sage_head_kernel(
    const float* __restrict__ x, const int* __restrict__ idx,
    const float* __restrict__ W1, const float* __restrict__ b1,
    const float* __restrict__ W2, const float* __restrict__ b2,
    const float* __restrict__ Wo, const float* __restrict__ bo,
    float* __restrict__ out)
{
    head_compute(x, idx, W1, b1, W2, b2, Wo, bo, out);
}

// ---------------------------------------------------------------------------
// Kernel 2: mp[b,n,:] = mean_k dequant(xq[b, idx[b,n,k], :])
// One wave per 4 nodes; 16 row-loads (uint2) hoisted for MLP.
// mp = (sum_r s_r*q_{r,c} - 128*sum_r s_r) / 16
// ---------------------------------------------------------------------------
__global__ __launch_bounds__(256) void sage_mp_i8_kernel(
    const unsigned char* __restrict__ xq,
    const float*         __restrict__ scales,
    const int*           __restrict__ idx,
    float*               __restrict__ mp_out)
{
    int wave = (blockIdx.x * 256 + threadIdx.x) >> 6;
    int lane = threadIdx.x & 63;
    int g = lane >> 4, c = lane & 15;
    int node0 = wave * 4;                      // 200000 % 4 == 0, batch-aligned
    int bofs = (node0 >= Nn) ? Nn : 0;
    const unsigned char* xb = xq + (size_t)bofs * Ff;
    const float* sb = scales + bofs;
    const int* ip = idx + (size_t)node0 * Kk;

    int   pre[4];
    float sv[4];
#pragma unroll
    for (int u = 0; u < 4; ++u) pre[u] = ip[u * 16 + c];
#pragma unroll
    for (int u = 0; u < 4; ++u) sv[u] = sb[pre[u]];

    uint2 v[4][4];
    float sc[4][4];
#pragma unroll
    for (int t = 0; t < 4; ++t) {
        int src = t * 4 + g;
#pragma unroll
        for (int u = 0; u < 4; ++u) {
            int r = __shfl(pre[u], src, 64);
            sc[u][t] = __shfl(sv[u], src, 64);
            v[u][t] = *(const uint2*)(xb + (size_t)r * Ff + c * 8);
        }
    }

#pragma unroll
    for (int u = 0; u < 4; ++u) {
        float acc[8];
#pragma unroll
        for (int j = 0; j < 8; ++j) acc[j] = 0.f;
        float ssum = 0.f;
#pragma unroll
        for (int t = 0; t < 4; ++t) {
            float s = sc[u][t];
            ssum += s;
            unsigned av = v[u][t].x, bw = v[u][t].y;
            acc[0] = fmaf(s, (float)(av & 0xffu),         acc[0]);
            acc[1] = fmaf(s, (float)((av >> 8) & 0xffu),  acc[1]);
            acc[2] = fmaf(s, (float)((av >> 16) & 0xffu), acc[2]);
            acc[3] = fmaf(s, (float)(av >> 24),           acc[3]);
            acc[4] = fmaf(s, (float)(bw & 0xffu),         acc[4]);
            acc[5] = fmaf(s, (float)((bw >> 8) & 0xffu),  acc[5]);
            acc[6] = fmaf(s, (float)((bw >> 16) & 0xffu), acc[6]);
            acc[7] = fmaf(s, (float)(bw >> 24),           acc[7]);
        }
#pragma unroll
        for (int j = 0; j < 8; ++j) {
            acc[j] += __shfl_xor(acc[j], 16, 64);
            acc[j] += __shfl_xor(acc[j], 32, 64);
        }
        ssum += __shfl_xor(ssum, 16, 64);
        ssum += __shfl_xor(ssum, 32, 64);

        int nd = node0 + u;
        float r0 = (acc[2 * g]     - 128.f * ssum) * (1.f / 16.f);
        float r1 = (acc[2 * g + 1] - 128.f * ssum) * (1.f / 16.f);
        float* op = mp_out + (size_t)nd * Ff + c * 8 + 2 * g;
        union { float2 f; unsigned long long u64; } cv;
        cv.f = make_float2(r0, r1);
        __builtin_nontemporal_store(cv.u64, (unsigned long long*)op);
    }
}

// ---------------------------------------------------------------------------
// Fallback f32 gather (only if ws too small)
// ---------------------------------------------------------------------------
__global__ __launch_bounds__(256) void sage_mp_kernel(
    const float* __restrict__ x,
    const int*   __restrict__ idx,
    float*       __restrict__ mp_out)
{
    int node = blockIdx.x * 4 + (threadIdx.x >> 6);
    if (node >= Bb * Nn) return;
    int lane = threadIdx.x & 63;
    const float* xb = x + (node >= Nn ? (size_t)Nn * Ff : 0);
    const int* ip = idx + (size_t)node * Kk;
    float2 acc = make_float2(0.f, 0.f);
#pragma unroll
    for (int k = 0; k < Kk; ++k) {
        float2 v = ((const float2*)(xb + (size_t)ip[k] * Ff))[lane];
        acc.x += v.x; acc.y += v.y;
    }
    acc.x *= (1.0f / Kk); acc.y *= (1.0f / Kk);
    ((float2*)(mp_out + (size_t)node * Ff))[lane] = acc;
}

extern "C" void kernel_launch(void* const* d_in, const int* in_sizes, int n_in,
                              void* d_out, int out_size, void* d_ws, size_t ws_size,
                              hipStream_t stream) {
    const float* x   = (const float*)d_in[0];
    const int*   idx = (const int*)d_in[1];
    const float* W1  = (const float*)d_in[2];
    const float* b1  = (const float*)d_in[3];
    const float* W2  = (const float*)d_in[4];
    const float* b2  = (const float*)d_in[5];
    const float* Wo  = (const float*)d_in[6];
    const float* bo  = (const float*)d_in[7];

    float* out    = (float*)d_out;
    float* mp_out = out + Bb * Cc;   // mp at 80B offset (16B aligned)

    const size_t need = (size_t)QROWS * Ff + (size_t)QROWS * 4;  // 26.4 MB

    if (ws_size >= need) {
        unsigned char* xq = (unsigned char*)d_ws;
        float* scales = (float*)((unsigned char*)d_ws + (size_t)QROWS * Ff);
        quant_kernel<<<QBLOCKS, 256, 0, stream>>>(x, xq, scales);
        sage_head_kernel<<<1, 128, 0, stream>>>(x, idx, W1, b1, W2, b2, Wo, bo, out);
        sage_mp_i8_kernel<<<QBLOCKS, 256, 0, stream>>>(xq, scales, idx, mp_out);
    } else {
        sage_mp_kernel<<<(Bb * Nn + 3) / 4, 256, 0, stream>>>(x, idx, mp_out);
        sage_head_kernel<<<1, 128, 0, stream>>>(x, idx, W1, b1, W2, b2, Wo, bo, out);
    }
}